// Round 7
// baseline (1630.035 us; speedup 1.0000x reference)
//
#include <hip/hip_runtime.h>

// PositionAwareAttention: S=8192, B=64, D=512, A=256, all fp32 I/O.
// R7: R4's proven shape (512 thr, BM=64, W packed from global, 2 blocks/CU,
// 16 waves/CU) made persistent over 16 tiles. Next tile's 16 x-loads are
// issued AFTER the K-loop (K-loop W-waits see an empty vmcnt queue) and stay
// in flight across softmax/wsum/out phases via RAW s_barrier (no vmcnt(0)
// drain; LDS ordering via explicit lgkmcnt(0) + sched_barrier(0) flanks).
// wsum reads x from fp16 REGS (not LDS) -> xs has no post-K-loop readers,
// red overlays xs. Both resident blocks keep ~128 KB each in flight through
// their stall windows -> HBM saturated.
// k3 combines 128 tile-partials per b. bt omitted (softmax shift-invariant).

#define S_DIM 8192
#define B_DIM 64
#define D_DIM 512
#define A_DIM 256
#define BM 64
#define NTILES 128
#define TPB 16            // tiles per block
#define NBLK 512          // 64 b x 8 sgrp -> 2 blocks/CU

typedef _Float16 half8 __attribute__((ext_vector_type(8)));
typedef float f32x4 __attribute__((ext_vector_type(4)));

// LDS: xs[64][512] f16 (65536; red[8][512] f32 overlays first 16 KiB after
// the K-loop) + scorep[4][64] + whb_s[256] + wt_s[256]
#define SMEM_MAIN (65536 + (256 + 256 + 256) * 4)

// Raw barrier: does NOT drain vmcnt (prefetch stays in flight).
#define BAR() do { __builtin_amdgcn_sched_barrier(0); \
  asm volatile("s_waitcnt lgkmcnt(0)" ::: "memory"); \
  __builtin_amdgcn_s_barrier(); \
  __builtin_amdgcn_sched_barrier(0); } while (0)

__device__ __forceinline__ float tanh_fast(float x) {
  // tanh(x) = 1 - 2/(exp(2x)+1); exp->inf/0 saturates correctly to +/-1
  float e = __expf(2.0f * x);
  return 1.0f - 2.0f * __builtin_amdgcn_rcpf(e + 1.0f);
}

// Pack Wx (A=256 x K=512 f32) -> fp16 fragment tiles (R4 layout).
// elem (a=ta*16+fr, k=tk*32+fg*8+j) at Wp[(ta*16+tk)*512 + (fg*16+fr)*8 + j]
__global__ void __launch_bounds__(256)
convw_kernel(const float* __restrict__ Wx, _Float16* __restrict__ Wp) {
  const int idx = (blockIdx.x * 256 + threadIdx.x) * 8;
  const int a = idx >> 9;
  const int k = idx & 511;
  f32x4 va = *(const f32x4*)(Wx + idx);
  f32x4 vb = *(const f32x4*)(Wx + idx + 4);
  half8 hx;
#pragma unroll
  for (int i = 0; i < 4; ++i) { hx[i] = (_Float16)va[i]; hx[4 + i] = (_Float16)vb[i]; }
  const int ta = a >> 4, fr = a & 15;
  const int tk = k >> 5, fg = (k >> 3) & 3;
  *(half8*)(Wp + (ta * 16 + tk) * 512 + (fg * 16 + fr) * 8) = hx;
}

__global__ void __launch_bounds__(256)
whb_kernel(const float* __restrict__ h, const float* __restrict__ Wh,
           const float* __restrict__ bx, float* __restrict__ whb) {
  __shared__ float hs[D_DIM];
  const int b = blockIdx.x, tid = threadIdx.x;
  hs[tid] = h[b * D_DIM + tid];
  hs[tid + 256] = h[b * D_DIM + 256 + tid];
  __syncthreads();
  const int g = tid >> 4, i = tid & 15;
  for (int pass = 0; pass < 16; ++pass) {
    const int a = pass * 16 + g;
    const f32x4* wrow = (const f32x4*)(Wh + (size_t)a * D_DIM);
    float dot = 0.f;
#pragma unroll
    for (int k = 0; k < 8; ++k) {
      f32x4 wv = wrow[i + k * 16];
      f32x4 hv = *(const f32x4*)(hs + (i + k * 16) * 4);
      dot += wv[0] * hv[0] + wv[1] * hv[1] + wv[2] * hv[2] + wv[3] * hv[3];
    }
#pragma unroll
    for (int mask = 1; mask < 16; mask <<= 1) dot += __shfl_xor(dot, mask, 64);
    if (i == 0) whb[b * A_DIM + a] = dot + bx[a];
  }
}

__global__ void __launch_bounds__(512, 4)
paa_main(const float* __restrict__ x, const _Float16* __restrict__ Wp,
         const float* __restrict__ whb, const float* __restrict__ Wt,
         float* __restrict__ m_arr, float* __restrict__ l_arr,
         float* __restrict__ acc_arr) {
  extern __shared__ char smem[];
  _Float16* xs = (_Float16*)smem;                 // [64][512] f16, chunk XOR swizzle
  float* red = (float*)smem;                      // [8][512] overlays xs post-K-loop
  float* scorep = (float*)(smem + 65536);         // [4][64]
  float* whb_s = scorep + 256;                    // [256]
  float* wt_s = whb_s + 256;                      // [256]

  const int tid = threadIdx.x;
  const int lane = tid & 63;
  const int wv = tid >> 6;
  const int b = blockIdx.x >> 3;
  const int sgrp = blockIdx.x & 7;
  const int t0 = sgrp * TPB;

  if (tid < A_DIM) { whb_s[tid] = whb[b * A_DIM + tid]; wt_s[tid] = Wt[tid]; }

  // staging map: row xr = tid/8 (1 row/thread logical), segment xj = tid%8
  const int xr = tid >> 3, xj = tid & 7;
  const int xj_sw = xj ^ (xr & 7);
  _Float16* xw = xs + xr * D_DIM + xj_sw * 8;

  // MFMA wave tiling (R4): wave = rows wm*32.., acols wn*64..
  const int wm = wv >> 2, wn = wv & 3;
  const int fr = lane & 15, fg = lane >> 4;
  const int a_row0 = wm * 32 + fr;
  const int akey = a_row0 & 7;
  const _Float16* wp = Wp + wn * 4 * 16 * 512 + lane * 8;

  f32x4 xa[8], xb[8];   // stage regs (in flight across raw barriers)
  half8 xh[8];          // fp16 copy of this thread's row segs (feeds wsum)

  // ---- prologue: stage tile t0
  {
    const float* xg = x + ((size_t)(t0 * BM + xr) * B_DIM + b) * D_DIM + xj * 8;
#pragma unroll
    for (int c = 0; c < 8; ++c) {
      xa[c] = *(const f32x4*)(xg + c * 64);
      xb[c] = *(const f32x4*)(xg + c * 64 + 4);
    }
#pragma unroll
    for (int c = 0; c < 8; ++c) {
#pragma unroll
      for (int j = 0; j < 4; ++j) { xh[c][j] = (_Float16)xa[c][j]; xh[c][4 + j] = (_Float16)xb[c][j]; }
      *(half8*)(xw + c * 64) = xh[c];
    }
  }
  BAR();   // W1: xs ready

  for (int i = 0; i < TPB; ++i) {
    const int t_idx = t0 + i;
    const bool pf = (i + 1 < TPB);

    // ---- K-loop: LDS A-frags + packed-global B-frags (vmcnt queue empty of
    // stage loads here -> compiler's bf waits are precise)
    f32x4 acc[2][4];
#pragma unroll
    for (int mi = 0; mi < 2; ++mi)
#pragma unroll
      for (int nf = 0; nf < 4; ++nf) acc[mi][nf] = (f32x4){0.f, 0.f, 0.f, 0.f};
#pragma unroll
    for (int c = 0; c < 8; ++c) {
#pragma unroll
      for (int kk = 0; kk < 2; ++kk) {
        const int tk = c * 2 + kk;
        const int slot = (c * 8 + kk * 4 + fg) ^ akey;
        half8 af0 = *(const half8*)(xs + a_row0 * D_DIM + slot * 8);
        half8 af1 = *(const half8*)(xs + (a_row0 + 16) * D_DIM + slot * 8);
        half8 bf0 = *(const half8*)(wp + (0 * 16 + tk) * 512);
        half8 bf1 = *(const half8*)(wp + (1 * 16 + tk) * 512);
        half8 bf2 = *(const half8*)(wp + (2 * 16 + tk) * 512);
        half8 bf3 = *(const half8*)(wp + (3 * 16 + tk) * 512);
        acc[0][0] = __builtin_amdgcn_mfma_f32_16x16x32_f16(af0, bf0, acc[0][0], 0, 0, 0);
        acc[0][1] = __builtin_amdgcn_mfma_f32_16x16x32_f16(af0, bf1, acc[0][1], 0, 0, 0);
        acc[0][2] = __builtin_amdgcn_mfma_f32_16x16x32_f16(af0, bf2, acc[0][2], 0, 0, 0);
        acc[0][3] = __builtin_amdgcn_mfma_f32_16x16x32_f16(af0, bf3, acc[0][3], 0, 0, 0);
        acc[1][0] = __builtin_amdgcn_mfma_f32_16x16x32_f16(af1, bf0, acc[1][0], 0, 0, 0);
        acc[1][1] = __builtin_amdgcn_mfma_f32_16x16x32_f16(af1, bf1, acc[1][1], 0, 0, 0);
        acc[1][2] = __builtin_amdgcn_mfma_f32_16x16x32_f16(af1, bf2, acc[1][2], 0, 0, 0);
        acc[1][3] = __builtin_amdgcn_mfma_f32_16x16x32_f16(af1, bf3, acc[1][3], 0, 0, 0);
      }
    }

    // ---- epilogue: score partial (C frag: row=fg*4+reg, col=fr)
    float part[2][4];
#pragma unroll
    for (int mi = 0; mi < 2; ++mi)
#pragma unroll
      for (int r = 0; r < 4; ++r) part[mi][r] = 0.f;
#pragma unroll
    for (int nf = 0; nf < 4; ++nf) {
      const int a_idx = wn * 64 + nf * 16 + fr;
      const float wt_a = wt_s[a_idx];
      const float whb_a = whb_s[a_idx];
#pragma unroll
      for (int mi = 0; mi < 2; ++mi)
#pragma unroll
        for (int r = 0; r < 4; ++r)
          part[mi][r] += wt_a * tanh_fast(acc[mi][nf][r] + whb_a);
    }
#pragma unroll
    for (int mask = 1; mask < 16; mask <<= 1)
#pragma unroll
      for (int mi = 0; mi < 2; ++mi)
#pragma unroll
        for (int r = 0; r < 4; ++r) part[mi][r] += __shfl_xor(part[mi][r], mask, 64);
    if (fr == 0) {
#pragma unroll
      for (int mi = 0; mi < 2; ++mi)
#pragma unroll
        for (int r = 0; r < 4; ++r)
          scorep[wn * 64 + wm * 32 + mi * 16 + fg * 4 + r] = part[mi][r];
    }

    // ---- issue next tile's loads; they stay in flight across A, C, D
    if (pf) {
      const float* xg = x + ((size_t)((t_idx + 1) * BM + xr) * B_DIM + b) * D_DIM + xj * 8;
#pragma unroll
      for (int c = 0; c < 8; ++c) {
        xa[c] = *(const f32x4*)(xg + c * 64);
        xb[c] = *(const f32x4*)(xg + c * 64 + 4);
      }
    }

    BAR();   // A: scorep visible; K-loop xs reads done (red overlay now safe)

    // ---- softmax, computed redundantly by every wave (lane = row)
    float sv = scorep[lane] + scorep[64 + lane] + scorep[128 + lane] + scorep[192 + lane];
    float m = sv;
#pragma unroll
    for (int mask = 1; mask < 64; mask <<= 1) m = fmaxf(m, __shfl_xor(m, mask, 64));
    float p = __expf(sv - m);
    if (tid == 0) {
      float lsum = p;
      // lane 0 needs full sum; do it in-wave on wave 0 only below
    }
    {
      float lsum = p;
#pragma unroll
      for (int mask = 1; mask < 64; mask <<= 1) lsum += __shfl_xor(lsum, mask, 64);
      if (tid == 0) {
        m_arr[b * NTILES + t_idx] = m;
        l_arr[b * NTILES + t_idx] = lsum;
      }
    }

    // ---- weighted sum from fp16 regs: thread owns row xr, segs xj*8+c*64
    {
      const float pr = __shfl(p, xr, 64);
#pragma unroll
      for (int c = 0; c < 8; ++c) {
        float pa0 = pr * (float)xh[c][0], pa1 = pr * (float)xh[c][1];
        float pa2 = pr * (float)xh[c][2], pa3 = pr * (float)xh[c][3];
        float pa4 = pr * (float)xh[c][4], pa5 = pr * (float)xh[c][5];
        float pa6 = pr * (float)xh[c][6], pa7 = pr * (float)xh[c][7];
        // reduce over the wave's 8 rows (lanes with same lane&7)
#pragma unroll
        for (int mask = 8; mask < 64; mask <<= 1) {
          pa0 += __shfl_xor(pa0, mask, 64); pa1 += __shfl_xor(pa1, mask, 64);
          pa2 += __shfl_xor(pa2, mask, 64); pa3 += __shfl_xor(pa3, mask, 64);
          pa4 += __shfl_xor(pa4, mask, 64); pa5 += __shfl_xor(pa5, mask, 64);
          pa6 += __shfl_xor(pa6, mask, 64); pa7 += __shfl_xor(pa7, mask, 64);
        }
        if (lane < 8) {
          float* rb = red + wv * 512 + lane * 8 + c * 64;
          *(f32x4*)(rb) = (f32x4){pa0, pa1, pa2, pa3};
          *(f32x4*)(rb + 4) = (f32x4){pa4, pa5, pa6, pa7};
        }
      }
    }

    BAR();   // C: red ready

    {
      float s = 0.f;
#pragma unroll
      for (int w2 = 0; w2 < 8; ++w2) s += red[w2 * 512 + tid];
      acc_arr[((size_t)(b * NTILES + t_idx)) * D_DIM + tid] = s;
    }

    if (pf) {
      BAR();   // D: red consumed -> xs free for overwrite
      // consume stage loads (compiler inserts the precise vmcnt wait here)
#pragma unroll
      for (int c = 0; c < 8; ++c) {
#pragma unroll
        for (int j = 0; j < 4; ++j) { xh[c][j] = (_Float16)xa[c][j]; xh[c][4 + j] = (_Float16)xb[c][j]; }
        *(half8*)(xw + c * 64) = xh[c];
      }
      BAR();   // W1: xs ready for next K-loop
    }
  }
}

__global__ void __launch_bounds__(512)
combine_kernel(const float* __restrict__ m_arr, const float* __restrict__ l_arr,
               const float* __restrict__ acc_arr, float* __restrict__ out) {
  __shared__ float ml[NTILES], ls[NTILES], wl[NTILES];
  const int b = blockIdx.x, tid = threadIdx.x;
  if (tid < NTILES) {
    ml[tid] = m_arr[b * NTILES + tid];
    ls[tid] = l_arr[b * NTILES + tid];
  }
  __syncthreads();
  float M = -1e30f;
  for (int i = 0; i < NTILES; ++i) M = fmaxf(M, ml[i]);
  if (tid < NTILES) wl[tid] = __expf(ml[tid] - M);
  __syncthreads();
  float L = 0.f;
  for (int i = 0; i < NTILES; ++i) L += wl[i] * ls[i];
  float sum = 0.f;
  const size_t base = (size_t)b * NTILES * D_DIM + tid;
  for (int i = 0; i < NTILES; ++i) sum += wl[i] * acc_arr[base + (size_t)i * D_DIM];
  out[b * D_DIM + tid] = sum / L;
}

extern "C" void kernel_launch(void* const* d_in, const int* in_sizes, int n_in,
                              void* d_out, int out_size, void* d_ws, size_t ws_size,
                              hipStream_t stream) {
  const float* x = (const float*)d_in[0];
  const float* h = (const float*)d_in[1];
  const float* Wx = (const float*)d_in[2];
  const float* bx = (const float*)d_in[3];
  const float* Wh = (const float*)d_in[4];
  const float* Wt = (const float*)d_in[5];
  // d_in[6] = bt: unused (softmax shift-invariant)

  char* ws = (char*)d_ws;
  _Float16* Wp = (_Float16*)ws;                               // 262144 B (packed)
  float* whb = (float*)(ws + 262144);                         // 65536 B
  float* m_arr = (float*)(ws + 262144 + 65536);               // 32768 B
  float* l_arr = (float*)(ws + 262144 + 65536 + 32768);       // 32768 B
  float* acc_arr = (float*)(ws + 262144 + 65536 + 65536);     // 16.8 MB

  hipFuncSetAttribute(reinterpret_cast<const void*>(paa_main),
                      hipFuncAttributeMaxDynamicSharedMemorySize, SMEM_MAIN);

  hipLaunchKernelGGL(convw_kernel, dim3(64), dim3(256), 0, stream, Wx, Wp);
  hipLaunchKernelGGL(whb_kernel, dim3(B_DIM), dim3(256), 0, stream, h, Wh, bx, whb);
  hipLaunchKernelGGL(paa_main, dim3(NBLK), dim3(512), SMEM_MAIN, stream,
                     x, Wp, whb, Wt, m_arr, l_arr, acc_arr);
  hipLaunchKernelGGL(combine_kernel, dim3(B_DIM), dim3(512), 0, stream,
                     m_arr, l_arr, acc_arr, (float*)d_out);
}

// Round 8
// 932.008 us; speedup vs baseline: 1.7489x; 1.7489x over previous
//
#include <hip/hip_runtime.h>

// PositionAwareAttention: S=8192, B=64, D=512, A=256, all fp32 I/O.
// R8: producer/consumer waves INSIDE one 16-wave block (1024 thr, 1 block/CU).
//   consumers (wv 0-7): R4's proven K-loop: wx = x.W^T via f16 MFMA, A-frags
//     from swizzled LDS, B-frags streamed from packed global W (L2). 2/SIMD.
//   producers (wv 8-15): stage tile i+1 fp32->fp16 into the other LDS buffer.
//     vmcnt is per-wave -> producer HBM waits never stall consumer L2 waits.
//   wsum: column-parallel with shfl-tree reduce -> no red LDS, 2 barriers/tile.
// VGPR discipline (R7 lesson): peak ~90 << 128 cap; stage batches of 8 loads.
// k3 combines 128 tile-partials per b. bt omitted (softmax shift-invariant).

#define S_DIM 8192
#define B_DIM 64
#define D_DIM 512
#define A_DIM 256
#define BM 64
#define NTILES 128
#define TPB 32            // tiles per block
#define NBLK 256          // 64 b x 4 sgrp (1 block/CU)

typedef _Float16 half8 __attribute__((ext_vector_type(8)));
typedef float f32x4 __attribute__((ext_vector_type(4)));

// LDS: xs dbuf 2*65536 + scorep[4][64] + whb_s[256] + wt_s[256]
#define SMEM_MAIN (131072 + 1024 + 1024 + 1024)

__device__ __forceinline__ float tanh_fast(float x) {
  // tanh(x) = 1 - 2/(exp(2x)+1); exp->inf/0 saturates correctly to +/-1
  float e = __expf(2.0f * x);
  return 1.0f - 2.0f * __builtin_amdgcn_rcpf(e + 1.0f);
}

// Pack Wx (A=256 x K=512 f32) -> fp16 fragment tiles (R4 layout).
// elem (a=ta*16+fr, k=tk*32+fg*8+j) at Wp[(ta*16+tk)*512 + (fg*16+fr)*8 + j]
__global__ void __launch_bounds__(256)
convw_kernel(const float* __restrict__ Wx, _Float16* __restrict__ Wp) {
  const int idx = (blockIdx.x * 256 + threadIdx.x) * 8;
  const int a = idx >> 9;
  const int k = idx & 511;
  f32x4 va = *(const f32x4*)(Wx + idx);
  f32x4 vb = *(const f32x4*)(Wx + idx + 4);
  half8 hx;
#pragma unroll
  for (int i = 0; i < 4; ++i) { hx[i] = (_Float16)va[i]; hx[4 + i] = (_Float16)vb[i]; }
  const int ta = a >> 4, fr = a & 15;
  const int tk = k >> 5, fg = (k >> 3) & 3;
  *(half8*)(Wp + (ta * 16 + tk) * 512 + (fg * 16 + fr) * 8) = hx;
}

__global__ void __launch_bounds__(256)
whb_kernel(const float* __restrict__ h, const float* __restrict__ Wh,
           const float* __restrict__ bx, float* __restrict__ whb) {
  __shared__ float hs[D_DIM];
  const int b = blockIdx.x, tid = threadIdx.x;
  hs[tid] = h[b * D_DIM + tid];
  hs[tid + 256] = h[b * D_DIM + 256 + tid];
  __syncthreads();
  const int g = tid >> 4, i = tid & 15;
  for (int pass = 0; pass < 16; ++pass) {
    const int a = pass * 16 + g;
    const f32x4* wrow = (const f32x4*)(Wh + (size_t)a * D_DIM);
    float dot = 0.f;
#pragma unroll
    for (int k = 0; k < 8; ++k) {
      f32x4 wv = wrow[i + k * 16];
      f32x4 hv = *(const f32x4*)(hs + (i + k * 16) * 4);
      dot += wv[0] * hv[0] + wv[1] * hv[1] + wv[2] * hv[2] + wv[3] * hv[3];
    }
#pragma unroll
    for (int mask = 1; mask < 16; mask <<= 1) dot += __shfl_xor(dot, mask, 64);
    if (i == 0) whb[b * A_DIM + a] = dot + bx[a];
  }
}

__global__ void __launch_bounds__(1024, 4)
paa_main(const float* __restrict__ x, const _Float16* __restrict__ Wp,
         const float* __restrict__ whb, const float* __restrict__ Wt,
         float* __restrict__ m_arr, float* __restrict__ l_arr,
         float* __restrict__ acc_arr) {
  extern __shared__ char smem[];
  _Float16* xs0 = (_Float16*)smem;                 // [64][512] f16, chunk XOR swizzle
  _Float16* xs1 = (_Float16*)(smem + 65536);
  float* scorep = (float*)(smem + 131072);         // [4][64]
  float* whb_s = scorep + 256;                     // [256]
  float* wt_s = whb_s + 256;                       // [256]

  const int tid = threadIdx.x;       // 0..1023
  const int lane = tid & 63;
  const int wv = tid >> 6;           // 0..15
  const int b = blockIdx.x >> 2;
  const int sgrp = blockIdx.x & 3;
  const int t0 = sgrp * TPB;

  if (tid < A_DIM) { whb_s[tid] = whb[b * A_DIM + tid]; wt_s[tid] = Wt[tid]; }

  const int fr = lane & 15, fg = lane >> 4;
  // consumer geometry (wv<8): R4 layout — rows wm*32.., acols wn*64..
  const int wm = (wv >> 2) & 1, wn = wv & 3;
  const int a_row0 = wm * 32 + fr;
  const int akey = fr & 7;
  const _Float16* wp = Wp + wn * 4 * 16 * 512 + lane * 8;
  // producer geometry (wv>=8): 8 rows per wave, 8 lanes per row
  const int prow = (wv - 8) * 8 + (lane >> 3);   // 0..63
  const int pj = lane & 7;                       // 8-f32 segment within row

  // ---- prologue: all 16 waves stage tile t0 into xs0
  {
    const int r = tid >> 4, j = tid & 15;        // 64 rows x 16 segs
    const float* rp = x + ((size_t)(t0 * BM + r) * B_DIM + b) * D_DIM;
    f32x4 xa[4], xb[4];
#pragma unroll
    for (int c = 0; c < 4; ++c) {
      xa[c] = *(const f32x4*)(rp + (j + c * 16) * 8);
      xb[c] = *(const f32x4*)(rp + (j + c * 16) * 8 + 4);
    }
#pragma unroll
    for (int c = 0; c < 4; ++c) {
      half8 hx;
#pragma unroll
      for (int q = 0; q < 4; ++q) { hx[q] = (_Float16)xa[c][q]; hx[4 + q] = (_Float16)xb[c][q]; }
      *(half8*)(xs0 + r * D_DIM + (((j + c * 16) ^ (r & 7)) * 8)) = hx;
    }
  }
  __syncthreads();

  for (int i = 0; i < TPB; ++i) {
    const int t_idx = t0 + i;
    _Float16* xcur = (i & 1) ? xs1 : xs0;
    _Float16* xnxt = (i & 1) ? xs0 : xs1;
    const bool pf = (i + 1 < TPB);

    if (wv < 8) {
      // ================= consumer: K-loop + epilogue =================
      f32x4 acc[2][4];
#pragma unroll
      for (int mi = 0; mi < 2; ++mi)
#pragma unroll
        for (int nf = 0; nf < 4; ++nf) acc[mi][nf] = (f32x4){0.f, 0.f, 0.f, 0.f};
#pragma unroll
      for (int tk = 0; tk < 16; ++tk) {
        const int slot = (tk * 4 + fg) ^ akey;
        half8 af0 = *(const half8*)(xcur + a_row0 * D_DIM + slot * 8);
        half8 af1 = *(const half8*)(xcur + (a_row0 + 16) * D_DIM + slot * 8);
        half8 bf0 = *(const half8*)(wp + (0 * 16 + tk) * 512);
        half8 bf1 = *(const half8*)(wp + (1 * 16 + tk) * 512);
        half8 bf2 = *(const half8*)(wp + (2 * 16 + tk) * 512);
        half8 bf3 = *(const half8*)(wp + (3 * 16 + tk) * 512);
        acc[0][0] = __builtin_amdgcn_mfma_f32_16x16x32_f16(af0, bf0, acc[0][0], 0, 0, 0);
        acc[0][1] = __builtin_amdgcn_mfma_f32_16x16x32_f16(af0, bf1, acc[0][1], 0, 0, 0);
        acc[0][2] = __builtin_amdgcn_mfma_f32_16x16x32_f16(af0, bf2, acc[0][2], 0, 0, 0);
        acc[0][3] = __builtin_amdgcn_mfma_f32_16x16x32_f16(af0, bf3, acc[0][3], 0, 0, 0);
        acc[1][0] = __builtin_amdgcn_mfma_f32_16x16x32_f16(af1, bf0, acc[1][0], 0, 0, 0);
        acc[1][1] = __builtin_amdgcn_mfma_f32_16x16x32_f16(af1, bf1, acc[1][1], 0, 0, 0);
        acc[1][2] = __builtin_amdgcn_mfma_f32_16x16x32_f16(af1, bf2, acc[1][2], 0, 0, 0);
        acc[1][3] = __builtin_amdgcn_mfma_f32_16x16x32_f16(af1, bf3, acc[1][3], 0, 0, 0);
      }
      // epilogue: score partial (C frag: row=fg*4+reg, col=fr)
      float part[2][4];
#pragma unroll
      for (int mi = 0; mi < 2; ++mi)
#pragma unroll
        for (int r = 0; r < 4; ++r) part[mi][r] = 0.f;
#pragma unroll
      for (int nf = 0; nf < 4; ++nf) {
        const int a_idx = wn * 64 + nf * 16 + fr;
        const float wt_a = wt_s[a_idx];
        const float whb_a = whb_s[a_idx];
#pragma unroll
        for (int mi = 0; mi < 2; ++mi)
#pragma unroll
          for (int r = 0; r < 4; ++r)
            part[mi][r] += wt_a * tanh_fast(acc[mi][nf][r] + whb_a);
      }
#pragma unroll
      for (int mask = 1; mask < 16; mask <<= 1)
#pragma unroll
        for (int mi = 0; mi < 2; ++mi)
#pragma unroll
          for (int r = 0; r < 4; ++r) part[mi][r] += __shfl_xor(part[mi][r], mask, 64);
      if (fr == 0) {
#pragma unroll
        for (int mi = 0; mi < 2; ++mi)
#pragma unroll
          for (int r = 0; r < 4; ++r)
            scorep[wn * 64 + wm * 32 + mi * 16 + fg * 4 + r] = part[mi][r];
      }
    } else if (pf) {
      // ================= producer: stage tile i+1 =================
      const float* rp = x + ((size_t)((t_idx + 1) * BM + prow) * B_DIM + b) * D_DIM;
      f32x4 xa[4], xb[4];
#pragma unroll
      for (int c = 0; c < 4; ++c) {      // batch 1: chunks pj + c*8, c=0..3
        xa[c] = *(const f32x4*)(rp + (pj + c * 8) * 8);
        xb[c] = *(const f32x4*)(rp + (pj + c * 8) * 8 + 4);
      }
#pragma unroll
      for (int c = 0; c < 4; ++c) {
        half8 hx;
#pragma unroll
        for (int q = 0; q < 4; ++q) { hx[q] = (_Float16)xa[c][q]; hx[4 + q] = (_Float16)xb[c][q]; }
        *(half8*)(xnxt + prow * D_DIM + (((pj + c * 8) ^ (prow & 7)) * 8)) = hx;
      }
#pragma unroll
      for (int c = 0; c < 4; ++c) {      // batch 2: chunks pj + 32 + c*8
        xa[c] = *(const f32x4*)(rp + (pj + 32 + c * 8) * 8);
        xb[c] = *(const f32x4*)(rp + (pj + 32 + c * 8) * 8 + 4);
      }
#pragma unroll
      for (int c = 0; c < 4; ++c) {
        half8 hx;
#pragma unroll
        for (int q = 0; q < 4; ++q) { hx[q] = (_Float16)xa[c][q]; hx[4 + q] = (_Float16)xb[c][q]; }
        *(half8*)(xnxt + prow * D_DIM + (((pj + 32 + c * 8) ^ (prow & 7)) * 8)) = hx;
      }
    }

    __syncthreads();   // A: scorep + xnxt ready

    // ---- softmax (computed redundantly by every wave; lane = row)
    float sv = scorep[lane] + scorep[64 + lane] + scorep[128 + lane] + scorep[192 + lane];
    float m = sv;
#pragma unroll
    for (int mask = 1; mask < 64; mask <<= 1) m = fmaxf(m, __shfl_xor(m, mask, 64));
    float p = __expf(sv - m);
    {
      float lsum = p;
#pragma unroll
      for (int mask = 1; mask < 64; mask <<= 1) lsum += __shfl_xor(lsum, mask, 64);
      if (tid == 0) {
        m_arr[b * NTILES + t_idx] = m;
        l_arr[b * NTILES + t_idx] = lsum;
      }
    }

    // ---- weighted sum, column-parallel: wave wv owns chunks wv*4..wv*4+3
    {
      float wacc[8];
#pragma unroll
      for (int q = 0; q < 8; ++q) wacc[q] = 0.f;
      const int chunk = wv * 4 + (lane & 3);
#pragma unroll
      for (int k = 0; k < 4; ++k) {
        const int row = k * 16 + (lane >> 2);
        const float prw = __shfl(p, row, 64);
        half8 v = *(const half8*)(xcur + row * D_DIM + ((chunk ^ (row & 7)) * 8));
#pragma unroll
        for (int q = 0; q < 8; ++q) wacc[q] += prw * (float)v[q];
      }
#pragma unroll
      for (int mask = 4; mask < 64; mask <<= 1)
#pragma unroll
        for (int q = 0; q < 8; ++q) wacc[q] += __shfl_xor(wacc[q], mask, 64);
      if (lane < 4) {
        float* ob = acc_arr + ((size_t)(b * NTILES + t_idx)) * D_DIM + (wv * 4 + lane) * 8;
        *(f32x4*)(ob) = (f32x4){wacc[0], wacc[1], wacc[2], wacc[3]};
        *(f32x4*)(ob + 4) = (f32x4){wacc[4], wacc[5], wacc[6], wacc[7]};
      }
    }

    __syncthreads();   // B: xcur reads + scorep reads done -> reusable next iter
  }
}

__global__ void __launch_bounds__(512)
combine_kernel(const float* __restrict__ m_arr, const float* __restrict__ l_arr,
               const float* __restrict__ acc_arr, float* __restrict__ out) {
  __shared__ float ml[NTILES], ls[NTILES], wl[NTILES];
  const int b = blockIdx.x, tid = threadIdx.x;
  if (tid < NTILES) {
    ml[tid] = m_arr[b * NTILES + tid];
    ls[tid] = l_arr[b * NTILES + tid];
  }
  __syncthreads();
  float M = -1e30f;
  for (int i = 0; i < NTILES; ++i) M = fmaxf(M, ml[i]);
  if (tid < NTILES) wl[tid] = __expf(ml[tid] - M);
  __syncthreads();
  float L = 0.f;
  for (int i = 0; i < NTILES; ++i) L += wl[i] * ls[i];
  float sum = 0.f;
  const size_t base = (size_t)b * NTILES * D_DIM + tid;
  for (int i = 0; i < NTILES; ++i) sum += wl[i] * acc_arr[base + (size_t)i * D_DIM];
  out[b * D_DIM + tid] = sum / L;
}

extern "C" void kernel_launch(void* const* d_in, const int* in_sizes, int n_in,
                              void* d_out, int out_size, void* d_ws, size_t ws_size,
                              hipStream_t stream) {
  const float* x = (const float*)d_in[0];
  const float* h = (const float*)d_in[1];
  const float* Wx = (const float*)d_in[2];
  const float* bx = (const float*)d_in[3];
  const float* Wh = (const float*)d_in[4];
  const float* Wt = (const float*)d_in[5];
  // d_in[6] = bt: unused (softmax shift-invariant)

  char* ws = (char*)d_ws;
  _Float16* Wp = (_Float16*)ws;                               // 262144 B (packed)
  float* whb = (float*)(ws + 262144);                         // 65536 B
  float* m_arr = (float*)(ws + 262144 + 65536);               // 32768 B
  float* l_arr = (float*)(ws + 262144 + 65536 + 32768);       // 32768 B
  float* acc_arr = (float*)(ws + 262144 + 65536 + 65536);     // 16.8 MB

  hipFuncSetAttribute(reinterpret_cast<const void*>(paa_main),
                      hipFuncAttributeMaxDynamicSharedMemorySize, SMEM_MAIN);

  hipLaunchKernelGGL(convw_kernel, dim3(64), dim3(256), 0, stream, Wx, Wp);
  hipLaunchKernelGGL(whb_kernel, dim3(B_DIM), dim3(256), 0, stream, h, Wh, bx, whb);
  hipLaunchKernelGGL(paa_main, dim3(NBLK), dim3(1024), SMEM_MAIN, stream,
                     x, Wp, whb, Wt, m_arr, l_arr, acc_arr);
  hipLaunchKernelGGL(combine_kernel, dim3(B_DIM), dim3(512), 0, stream,
                     m_arr, l_arr, acc_arr, (float*)d_out);
}

// Round 9
// 705.350 us; speedup vs baseline: 2.3110x; 1.3213x over previous
//
#include <hip/hip_runtime.h>

// PositionAwareAttention: S=8192, B=64, D=512, A=256, all fp32 I/O.
// R9: W IN REGISTERS with viable occupancy. One 16-wave block/CU (1024 thr,
// 256 blocks, 32 tiles each). Wave owns 16 acols -> wreg[16] half8 = 64 VGPR,
// loaded ONCE; 16 waves cover A=256. K-loop = pure LDS+MFMA (ZERO global
// loads / vmcnt ops) -> next tile's x-loads are issued before the K-loop and
// consumed after it; the in-flight window crosses only RAW s_barriers
// (lgkmcnt(0)+s_barrier, no vmcnt drain). Double-buffered 64 KiB fp16 x LDS.
// VGPR budget (R7 lesson): W 64 + acc 16 + stage 16 + temps ~ 120 <= 128.
// Removes the W-from-L2 inner loop that stalled R4/R8 (L2 thrash -> HBM).
// k3 combines 128 tile-partials per b. bt omitted (softmax shift-invariant).

#define S_DIM 8192
#define B_DIM 64
#define D_DIM 512
#define A_DIM 256
#define BM 64
#define NTILES 128
#define TPB 32            // tiles per block
#define NBLK 256          // 64 b x 4 sgrp (1 block/CU)

typedef _Float16 half8 __attribute__((ext_vector_type(8)));
typedef float f32x4 __attribute__((ext_vector_type(4)));

// LDS: xs dbuf 2*65536 + scorep[16][64] + whb_s[256] + wt_s[256]
#define SMEM_MAIN (131072 + 4096 + 1024 + 1024)

// Raw barrier: does NOT drain vmcnt (stage loads stay in flight).
#define BAR() do { __builtin_amdgcn_sched_barrier(0); \
  asm volatile("s_waitcnt lgkmcnt(0)" ::: "memory"); \
  __builtin_amdgcn_s_barrier(); \
  __builtin_amdgcn_sched_barrier(0); } while (0)

__device__ __forceinline__ float tanh_fast(float x) {
  // tanh(x) = 1 - 2/(exp(2x)+1); exp->inf/0 saturates correctly to +/-1
  float e = __expf(2.0f * x);
  return 1.0f - 2.0f * __builtin_amdgcn_rcpf(e + 1.0f);
}

// Pack Wx (A=256 x K=512 f32) -> fp16 fragment tiles (R4 layout).
// elem (a=ta*16+fr, k=tk*32+fg*8+j) at Wp[(ta*16+tk)*512 + (fg*16+fr)*8 + j]
__global__ void __launch_bounds__(256)
convw_kernel(const float* __restrict__ Wx, _Float16* __restrict__ Wp) {
  const int idx = (blockIdx.x * 256 + threadIdx.x) * 8;
  const int a = idx >> 9;
  const int k = idx & 511;
  f32x4 va = *(const f32x4*)(Wx + idx);
  f32x4 vb = *(const f32x4*)(Wx + idx + 4);
  half8 hx;
#pragma unroll
  for (int i = 0; i < 4; ++i) { hx[i] = (_Float16)va[i]; hx[4 + i] = (_Float16)vb[i]; }
  const int ta = a >> 4, fr = a & 15;
  const int tk = k >> 5, fg = (k >> 3) & 3;
  *(half8*)(Wp + (ta * 16 + tk) * 512 + (fg * 16 + fr) * 8) = hx;
}

__global__ void __launch_bounds__(256)
whb_kernel(const float* __restrict__ h, const float* __restrict__ Wh,
           const float* __restrict__ bx, float* __restrict__ whb) {
  __shared__ float hs[D_DIM];
  const int b = blockIdx.x, tid = threadIdx.x;
  hs[tid] = h[b * D_DIM + tid];
  hs[tid + 256] = h[b * D_DIM + 256 + tid];
  __syncthreads();
  const int g = tid >> 4, i = tid & 15;
  for (int pass = 0; pass < 16; ++pass) {
    const int a = pass * 16 + g;
    const f32x4* wrow = (const f32x4*)(Wh + (size_t)a * D_DIM);
    float dot = 0.f;
#pragma unroll
    for (int k = 0; k < 8; ++k) {
      f32x4 wv = wrow[i + k * 16];
      f32x4 hv = *(const f32x4*)(hs + (i + k * 16) * 4);
      dot += wv[0] * hv[0] + wv[1] * hv[1] + wv[2] * hv[2] + wv[3] * hv[3];
    }
#pragma unroll
    for (int mask = 1; mask < 16; mask <<= 1) dot += __shfl_xor(dot, mask, 64);
    if (i == 0) whb[b * A_DIM + a] = dot + bx[a];
  }
}

__global__ void __launch_bounds__(1024, 4)
paa_main(const float* __restrict__ x, const _Float16* __restrict__ Wp,
         const float* __restrict__ whb, const float* __restrict__ Wt,
         float* __restrict__ m_arr, float* __restrict__ l_arr,
         float* __restrict__ acc_arr) {
  extern __shared__ char smem[];
  _Float16* xs0 = (_Float16*)smem;                 // [64][512] f16, chunk XOR swizzle
  _Float16* xs1 = (_Float16*)(smem + 65536);
  float* scorep = (float*)(smem + 131072);         // [16][64]
  float* whb_s = scorep + 1024;                    // [256]
  float* wt_s = whb_s + 256;                       // [256]

  const int tid = threadIdx.x;       // 0..1023
  const int lane = tid & 63;
  const int wv = tid >> 6;           // 0..15
  const int b = blockIdx.x >> 2;
  const int sgrp = blockIdx.x & 3;
  const int t0 = sgrp * TPB;

  if (tid < A_DIM) { whb_s[tid] = whb[b * A_DIM + tid]; wt_s[tid] = Wt[tid]; }

  const int fr = lane & 15, fg = lane >> 4;
  const int akey = fr & 7;           // (mf*16+fr)&7 == fr&7

  // ---- persistent W: wave owns acols [wv*16, wv*16+16). 64 VGPR, loaded once.
  half8 wreg[16];
#pragma unroll
  for (int tk = 0; tk < 16; ++tk)
    wreg[tk] = *(const half8*)(Wp + (wv * 16 + tk) * 512 + lane * 8);

  // staging map: thread -> row srow = tid/16, 8-float seg sseg = tid%16 (x4 chunks)
  const int srow = tid >> 4, sseg = tid & 15;
  const int skey = srow & 7;

  auto cvw = [&](_Float16* buf, int c, f32x4 va, f32x4 vb) {
    half8 hx;
#pragma unroll
    for (int j = 0; j < 4; ++j) { hx[j] = (_Float16)va[j]; hx[4 + j] = (_Float16)vb[j]; }
    *(half8*)(buf + srow * D_DIM + (((c * 16 + sseg) ^ skey) * 8)) = hx;
  };

  // ---- prologue: stage tile t0 into xs0 (8 dwordx4 per thread)
  {
    const float* rp = x + ((size_t)(t0 * BM + srow) * B_DIM + b) * D_DIM + sseg * 8;
    f32x4 a0 = *(const f32x4*)(rp);           f32x4 b0 = *(const f32x4*)(rp + 4);
    f32x4 a1 = *(const f32x4*)(rp + 128);     f32x4 b1 = *(const f32x4*)(rp + 132);
    f32x4 a2 = *(const f32x4*)(rp + 256);     f32x4 b2 = *(const f32x4*)(rp + 260);
    f32x4 a3 = *(const f32x4*)(rp + 384);     f32x4 b3 = *(const f32x4*)(rp + 388);
    cvw(xs0, 0, a0, b0); cvw(xs0, 1, a1, b1);
    cvw(xs0, 2, a2, b2); cvw(xs0, 3, a3, b3);
  }
  __syncthreads();

  for (int i = 0; i < TPB; ++i) {
    const int t_idx = t0 + i;
    _Float16* xcur = (i & 1) ? xs1 : xs0;
    _Float16* xnxt = (i & 1) ? xs0 : xs1;
    const bool pf = (i + 1 < TPB);
    const float* rpn = x + ((size_t)((t_idx + 1) * BM + srow) * B_DIM + b) * D_DIM + sseg * 8;

    // ---- issue stage batch A (chunks 0,1 of tile i+1); stays in flight
    f32x4 A0, B0, A1, B1;
    if (pf) {
      A0 = *(const f32x4*)(rpn);        B0 = *(const f32x4*)(rpn + 4);
      A1 = *(const f32x4*)(rpn + 128);  B1 = *(const f32x4*)(rpn + 132);
    }
    __builtin_amdgcn_sched_barrier(0);

    // ---- K-loop: pure LDS + MFMA (no vmcnt ops at all)
    f32x4 acc[4];
#pragma unroll
    for (int mf = 0; mf < 4; ++mf) acc[mf] = (f32x4){0.f, 0.f, 0.f, 0.f};
#pragma unroll
    for (int tk = 0; tk < 16; ++tk) {
      const int slot = (tk * 4 + fg) ^ akey;
      half8 af0 = *(const half8*)(xcur + (0 * 16 + fr) * D_DIM + slot * 8);
      half8 af1 = *(const half8*)(xcur + (1 * 16 + fr) * D_DIM + slot * 8);
      half8 af2 = *(const half8*)(xcur + (2 * 16 + fr) * D_DIM + slot * 8);
      half8 af3 = *(const half8*)(xcur + (3 * 16 + fr) * D_DIM + slot * 8);
      acc[0] = __builtin_amdgcn_mfma_f32_16x16x32_f16(af0, wreg[tk], acc[0], 0, 0, 0);
      acc[1] = __builtin_amdgcn_mfma_f32_16x16x32_f16(af1, wreg[tk], acc[1], 0, 0, 0);
      acc[2] = __builtin_amdgcn_mfma_f32_16x16x32_f16(af2, wreg[tk], acc[2], 0, 0, 0);
      acc[3] = __builtin_amdgcn_mfma_f32_16x16x32_f16(af3, wreg[tk], acc[3], 0, 0, 0);
    }

    // ---- consume A (latency hidden under K-loop), issue batch B (chunks 2,3)
    if (pf) {
      cvw(xnxt, 0, A0, B0);
      cvw(xnxt, 1, A1, B1);
      A0 = *(const f32x4*)(rpn + 256);  B0 = *(const f32x4*)(rpn + 260);
      A1 = *(const f32x4*)(rpn + 384);  B1 = *(const f32x4*)(rpn + 388);
    }
    __builtin_amdgcn_sched_barrier(0);

    // ---- epilogue: this wave's 16-acol score partial (C frag: row=fg*4+r, col=fr)
    {
      const float wt_a = wt_s[wv * 16 + fr];
      const float whb_a = whb_s[wv * 16 + fr];
#pragma unroll
      for (int mf = 0; mf < 4; ++mf) {
#pragma unroll
        for (int r = 0; r < 4; ++r) {
          float v = wt_a * tanh_fast(acc[mf][r] + whb_a);
#pragma unroll
          for (int mask = 1; mask < 16; mask <<= 1) v += __shfl_xor(v, mask, 64);
          if (fr == 0) scorep[wv * 64 + mf * 16 + fg * 4 + r] = v;
        }
      }
    }

    BAR();   // A: scorep visible; K-loop xs reads done. Batch-B loads stay live.

    // ---- softmax (computed redundantly by every wave; lane = row)
    float sv = 0.f;
#pragma unroll
    for (int w = 0; w < 16; ++w) sv += scorep[w * 64 + lane];
    float m = sv;
#pragma unroll
    for (int mask = 1; mask < 64; mask <<= 1) m = fmaxf(m, __shfl_xor(m, mask, 64));
    float p = __expf(sv - m);
    {
      float lsum = p;
#pragma unroll
      for (int mask = 1; mask < 64; mask <<= 1) lsum += __shfl_xor(lsum, mask, 64);
      if (tid == 0) {
        m_arr[b * NTILES + t_idx] = m;
        l_arr[b * NTILES + t_idx] = lsum;
      }
    }

    // ---- weighted sum, column-parallel: wave owns chunks wv*4..wv*4+3
    {
      float wacc[8];
#pragma unroll
      for (int q = 0; q < 8; ++q) wacc[q] = 0.f;
      const int chunk = wv * 4 + (lane & 3);
#pragma unroll
      for (int k = 0; k < 4; ++k) {
        const int row = k * 16 + (lane >> 2);
        const float prw = __shfl(p, row, 64);
        half8 v = *(const half8*)(xcur + row * D_DIM + ((chunk ^ (row & 7)) * 8));
#pragma unroll
        for (int q = 0; q < 8; ++q) wacc[q] += prw * (float)v[q];
      }
#pragma unroll
      for (int mask = 4; mask < 64; mask <<= 1)
#pragma unroll
        for (int q = 0; q < 8; ++q) wacc[q] += __shfl_xor(wacc[q], mask, 64);
      if (lane < 4) {
        float* ob = acc_arr + ((size_t)(b * NTILES + t_idx)) * D_DIM + (wv * 4 + lane) * 8;
        *(f32x4*)(ob) = (f32x4){wacc[0], wacc[1], wacc[2], wacc[3]};
        *(f32x4*)(ob + 4) = (f32x4){wacc[4], wacc[5], wacc[6], wacc[7]};
      }
    }

    // ---- consume B
    if (pf) {
      cvw(xnxt, 2, A0, B0);
      cvw(xnxt, 3, A1, B1);
    }

    BAR();   // B: xnxt complete + xcur reads done -> buffers swap safely
  }
}

__global__ void __launch_bounds__(512)
combine_kernel(const float* __restrict__ m_arr, const float* __restrict__ l_arr,
               const float* __restrict__ acc_arr, float* __restrict__ out) {
  __shared__ float ml[NTILES], ls[NTILES], wl[NTILES];
  const int b = blockIdx.x, tid = threadIdx.x;
  if (tid < NTILES) {
    ml[tid] = m_arr[b * NTILES + tid];
    ls[tid] = l_arr[b * NTILES + tid];
  }
  __syncthreads();
  float M = -1e30f;
  for (int i = 0; i < NTILES; ++i) M = fmaxf(M, ml[i]);
  if (tid < NTILES) wl[tid] = __expf(ml[tid] - M);
  __syncthreads();
  float L = 0.f;
  for (int i = 0; i < NTILES; ++i) L += wl[i] * ls[i];
  float sum = 0.f;
  const size_t base = (size_t)b * NTILES * D_DIM + tid;
  for (int i = 0; i < NTILES; ++i) sum += wl[i] * acc_arr[base + (size_t)i * D_DIM];
  out[b * D_DIM + tid] = sum / L;
}

extern "C" void kernel_launch(void* const* d_in, const int* in_sizes, int n_in,
                              void* d_out, int out_size, void* d_ws, size_t ws_size,
                              hipStream_t stream) {
  const float* x = (const float*)d_in[0];
  const float* h = (const float*)d_in[1];
  const float* Wx = (const float*)d_in[2];
  const float* bx = (const float*)d_in[3];
  const float* Wh = (const float*)d_in[4];
  const float* Wt = (const float*)d_in[5];
  // d_in[6] = bt: unused (softmax shift-invariant)

  char* ws = (char*)d_ws;
  _Float16* Wp = (_Float16*)ws;                               // 262144 B (packed)
  float* whb = (float*)(ws + 262144);                         // 65536 B
  float* m_arr = (float*)(ws + 262144 + 65536);               // 32768 B
  float* l_arr = (float*)(ws + 262144 + 65536 + 32768);       // 32768 B
  float* acc_arr = (float*)(ws + 262144 + 65536 + 65536);     // 16.8 MB

  hipFuncSetAttribute(reinterpret_cast<const void*>(paa_main),
                      hipFuncAttributeMaxDynamicSharedMemorySize, SMEM_MAIN);

  hipLaunchKernelGGL(convw_kernel, dim3(64), dim3(256), 0, stream, Wx, Wp);
  hipLaunchKernelGGL(whb_kernel, dim3(B_DIM), dim3(256), 0, stream, h, Wh, bx, whb);
  hipLaunchKernelGGL(paa_main, dim3(NBLK), dim3(1024), SMEM_MAIN, stream,
                     x, Wp, whb, Wt, m_arr, l_arr, acc_arr);
  hipLaunchKernelGGL(combine_kernel, dim3(B_DIM), dim3(512), 0, stream,
                     m_arr, l_arr, acc_arr, (float*)d_out);
}

// Round 10
// 698.768 us; speedup vs baseline: 2.3327x; 1.0094x over previous
//
#include <hip/hip_runtime.h>

// PositionAwareAttention: S=8192, B=64, D=512, A=256, all fp32 I/O.
// R10: LDS-pipe-bound fix (R9 PMC: LDS ~900K cyc/CU = the wall).
//  - 8 waves x (64 rows x 32 acols): wreg = 32 half8 = 128 VGPR/wave ->
//    K-loop LDS reads halved (512 KB/tile/CU). launch_bounds(512,2).
//  - fold-reduce epilogue: 30 shuffles + ONE ds_write (was 64 + 16).
//  - softmax+wsum on waves 0-3 only; waves 4-7 go straight to stage-consume.
//  - R9 raw-barrier prefetch skeleton kept (issue-A preK / consume-A postK /
//    issue-B / BAR / wsum | consume-B / BAR). No vmcnt drains at barriers.
// k3 combines 128 tile-partials per b. bt omitted (softmax shift-invariant).

#define S_DIM 8192
#define B_DIM 64
#define D_DIM 512
#define A_DIM 256
#define BM 64
#define NTILES 128
#define TPB 32            // tiles per block
#define NBLK 256          // 64 b x 4 sgrp (1 block/CU)

typedef _Float16 half8 __attribute__((ext_vector_type(8)));
typedef float f32x4 __attribute__((ext_vector_type(4)));

// LDS: xs dbuf 2*65536 + scorep[8][64]
#define SMEM_MAIN (131072 + 2048)

// Raw barrier: does NOT drain vmcnt (stage loads stay in flight).
#define BAR() do { __builtin_amdgcn_sched_barrier(0); \
  asm volatile("s_waitcnt lgkmcnt(0)" ::: "memory"); \
  __builtin_amdgcn_s_barrier(); \
  __builtin_amdgcn_sched_barrier(0); } while (0)

__device__ __forceinline__ float tanh_fast(float x) {
  // tanh(x) = 1 - 2/(exp(2x)+1); exp->inf/0 saturates correctly to +/-1
  float e = __expf(2.0f * x);
  return 1.0f - 2.0f * __builtin_amdgcn_rcpf(e + 1.0f);
}

// Pack Wx (A=256 x K=512 f32) -> fp16 fragment tiles (R4 layout).
// elem (a=ta*16+fr, k=tk*32+fg*8+j) at Wp[(ta*16+tk)*512 + (fg*16+fr)*8 + j]
__global__ void __launch_bounds__(256)
convw_kernel(const float* __restrict__ Wx, _Float16* __restrict__ Wp) {
  const int idx = (blockIdx.x * 256 + threadIdx.x) * 8;
  const int a = idx >> 9;
  const int k = idx & 511;
  f32x4 va = *(const f32x4*)(Wx + idx);
  f32x4 vb = *(const f32x4*)(Wx + idx + 4);
  half8 hx;
#pragma unroll
  for (int i = 0; i < 4; ++i) { hx[i] = (_Float16)va[i]; hx[4 + i] = (_Float16)vb[i]; }
  const int ta = a >> 4, fr = a & 15;
  const int tk = k >> 5, fg = (k >> 3) & 3;
  *(half8*)(Wp + (ta * 16 + tk) * 512 + (fg * 16 + fr) * 8) = hx;
}

__global__ void __launch_bounds__(256)
whb_kernel(const float* __restrict__ h, const float* __restrict__ Wh,
           const float* __restrict__ bx, float* __restrict__ whb) {
  __shared__ float hs[D_DIM];
  const int b = blockIdx.x, tid = threadIdx.x;
  hs[tid] = h[b * D_DIM + tid];
  hs[tid + 256] = h[b * D_DIM + 256 + tid];
  __syncthreads();
  const int g = tid >> 4, i = tid & 15;
  for (int pass = 0; pass < 16; ++pass) {
    const int a = pass * 16 + g;
    const f32x4* wrow = (const f32x4*)(Wh + (size_t)a * D_DIM);
    float dot = 0.f;
#pragma unroll
    for (int k = 0; k < 8; ++k) {
      f32x4 wv = wrow[i + k * 16];
      f32x4 hv = *(const f32x4*)(hs + (i + k * 16) * 4);
      dot += wv[0] * hv[0] + wv[1] * hv[1] + wv[2] * hv[2] + wv[3] * hv[3];
    }
#pragma unroll
    for (int mask = 1; mask < 16; mask <<= 1) dot += __shfl_xor(dot, mask, 64);
    if (i == 0) whb[b * A_DIM + a] = dot + bx[a];
  }
}

__global__ void __launch_bounds__(512, 2)
paa_main(const float* __restrict__ x, const _Float16* __restrict__ Wp,
         const float* __restrict__ whb, const float* __restrict__ Wt,
         float* __restrict__ m_arr, float* __restrict__ l_arr,
         float* __restrict__ acc_arr) {
  extern __shared__ char smem[];
  _Float16* xs0 = (_Float16*)smem;                 // [64][512] f16, chunk XOR swizzle
  _Float16* xs1 = (_Float16*)(smem + 65536);
  float* scorep = (float*)(smem + 131072);         // [8][64]

  const int tid = threadIdx.x;       // 0..511
  const int lane = tid & 63;
  const int wv = tid >> 6;           // 0..7
  const int b = blockIdx.x >> 2;
  const int sgrp = blockIdx.x & 3;
  const int t0 = sgrp * TPB;

  const int fr = lane & 15, fg = lane >> 4;
  const int akey = fr & 7;

  // ---- persistent W: wave owns acols [wv*32, wv*32+32). 128 VGPR, loaded once.
  half8 wreg[2][16];
#pragma unroll
  for (int nf = 0; nf < 2; ++nf)
#pragma unroll
    for (int tk = 0; tk < 16; ++tk)
      wreg[nf][tk] = *(const half8*)(Wp + ((wv * 2 + nf) * 16 + tk) * 512 + lane * 8);

  // hoisted epilogue constants (per-lane acol scalars)
  const float wt0  = Wt[wv * 32 + fr];
  const float wt1  = Wt[wv * 32 + 16 + fr];
  const float whb0 = whb[b * A_DIM + wv * 32 + fr];
  const float whb1 = whb[b * A_DIM + wv * 32 + 16 + fr];

  // staging map: row srow = tid/8, seg sseg = tid%8. Pair p: f32 cols
  // p*64 + sseg*8 .. +7  -> fp16 chunk ch = p*8 + sseg.
  const int srow = tid >> 3, sseg = tid & 7;
  const int skey = srow & 7;

  f32x4 sa[4], sb[4];   // stage batch regs (32 VGPR)

  auto issue_batch = [&](const float* rp, int pbase) {
#pragma unroll
    for (int p = 0; p < 4; ++p) {
      sa[p] = *(const f32x4*)(rp + (pbase + p) * 64 + sseg * 8);
      sb[p] = *(const f32x4*)(rp + (pbase + p) * 64 + sseg * 8 + 4);
    }
  };
  auto consume_batch = [&](_Float16* buf, int pbase) {
#pragma unroll
    for (int p = 0; p < 4; ++p) {
      half8 hx;
#pragma unroll
      for (int j = 0; j < 4; ++j) { hx[j] = (_Float16)sa[p][j]; hx[4 + j] = (_Float16)sb[p][j]; }
      const int ch = (pbase + p) * 8 + sseg;
      *(half8*)(buf + srow * D_DIM + ((ch ^ skey) * 8)) = hx;
    }
  };

  // ---- prologue: stage tile t0 into xs0 (both batches)
  {
    const float* rp = x + ((size_t)(t0 * BM + srow) * B_DIM + b) * D_DIM;
    issue_batch(rp, 0);
    consume_batch(xs0, 0);
    issue_batch(rp, 4);
    consume_batch(xs0, 4);
  }
  __syncthreads();

  for (int i = 0; i < TPB; ++i) {
    const int t_idx = t0 + i;
    _Float16* xcur = (i & 1) ? xs1 : xs0;
    _Float16* xnxt = (i & 1) ? xs0 : xs1;
    const bool pf = (i + 1 < TPB);
    const float* rpn = x + ((size_t)((t_idx + 1) * BM + srow) * B_DIM + b) * D_DIM;

    // ---- issue batch A of tile i+1 (in flight across the K-loop)
    if (pf) issue_batch(rpn, 0);
    __builtin_amdgcn_sched_barrier(0);

    // ---- K-loop: pure LDS + MFMA (no vmem ops)
    f32x4 acc[4][2];
#pragma unroll
    for (int mf = 0; mf < 4; ++mf)
#pragma unroll
      for (int nf = 0; nf < 2; ++nf) acc[mf][nf] = (f32x4){0.f, 0.f, 0.f, 0.f};
#pragma unroll
    for (int tk = 0; tk < 16; ++tk) {
      const int slot = ((tk * 4 + fg) ^ akey) * 8;
      half8 af0 = *(const half8*)(xcur + (fr) * D_DIM + slot);
      half8 af1 = *(const half8*)(xcur + (16 + fr) * D_DIM + slot);
      half8 af2 = *(const half8*)(xcur + (32 + fr) * D_DIM + slot);
      half8 af3 = *(const half8*)(xcur + (48 + fr) * D_DIM + slot);
      acc[0][0] = __builtin_amdgcn_mfma_f32_16x16x32_f16(af0, wreg[0][tk], acc[0][0], 0, 0, 0);
      acc[0][1] = __builtin_amdgcn_mfma_f32_16x16x32_f16(af0, wreg[1][tk], acc[0][1], 0, 0, 0);
      acc[1][0] = __builtin_amdgcn_mfma_f32_16x16x32_f16(af1, wreg[0][tk], acc[1][0], 0, 0, 0);
      acc[1][1] = __builtin_amdgcn_mfma_f32_16x16x32_f16(af1, wreg[1][tk], acc[1][1], 0, 0, 0);
      acc[2][0] = __builtin_amdgcn_mfma_f32_16x16x32_f16(af2, wreg[0][tk], acc[2][0], 0, 0, 0);
      acc[2][1] = __builtin_amdgcn_mfma_f32_16x16x32_f16(af2, wreg[1][tk], acc[2][1], 0, 0, 0);
      acc[3][0] = __builtin_amdgcn_mfma_f32_16x16x32_f16(af3, wreg[0][tk], acc[3][0], 0, 0, 0);
      acc[3][1] = __builtin_amdgcn_mfma_f32_16x16x32_f16(af3, wreg[1][tk], acc[3][1], 0, 0, 0);
    }

    // ---- consume A into xnxt (vmcnt wait fully covered by K-loop)
    if (pf) consume_batch(xnxt, 0);

    // ---- epilogue: v[16] partials, fold-reduce over the 16 fr-lanes
    {
      float v[16];
#pragma unroll
      for (int mf = 0; mf < 4; ++mf)
#pragma unroll
        for (int r = 0; r < 4; ++r)
          v[mf * 4 + r] = wt0 * tanh_fast(acc[mf][0][r] + whb0)
                        + wt1 * tanh_fast(acc[mf][1][r] + whb1);
      float w8[8];
#pragma unroll
      for (int j = 0; j < 8; ++j) {
        float e = v[2 * j]     + __shfl_xor(v[2 * j], 1, 64);
        float o = v[2 * j + 1] + __shfl_xor(v[2 * j + 1], 1, 64);
        w8[j] = (fr & 1) ? o : e;
      }
      float w4[4];
#pragma unroll
      for (int j = 0; j < 4; ++j) {
        float e = w8[2 * j]     + __shfl_xor(w8[2 * j], 2, 64);
        float o = w8[2 * j + 1] + __shfl_xor(w8[2 * j + 1], 2, 64);
        w4[j] = (fr & 2) ? o : e;
      }
      float w2[2];
#pragma unroll
      for (int j = 0; j < 2; ++j) {
        float e = w4[2 * j]     + __shfl_xor(w4[2 * j], 4, 64);
        float o = w4[2 * j + 1] + __shfl_xor(w4[2 * j + 1], 4, 64);
        w2[j] = (fr & 4) ? o : e;
      }
      float e = w2[0] + __shfl_xor(w2[0], 8, 64);
      float o = w2[1] + __shfl_xor(w2[1], 8, 64);
      float w1 = (fr & 8) ? o : e;
      // lane (fr,fg) holds the reduced value for row (fr>>2)*16 + fg*4 + (fr&3)
      scorep[wv * 64 + (fr >> 2) * 16 + fg * 4 + (fr & 3)] = w1;
    }

    // ---- issue batch B (in flight across BAR + softmax/wsum)
    if (pf) issue_batch(rpn, 4);

    BAR();   // A: scorep visible; K-loop xs reads done. Batch-B loads stay live.

    // ---- softmax + weighted sum: waves 0-3 only
    if (wv < 4) {
      float sv = 0.f;
#pragma unroll
      for (int w = 0; w < 8; ++w) sv += scorep[w * 64 + lane];
      float m = sv;
#pragma unroll
      for (int mask = 1; mask < 64; mask <<= 1) m = fmaxf(m, __shfl_xor(m, mask, 64));
      float p = __expf(sv - m);
      float lsum = p;
#pragma unroll
      for (int mask = 1; mask < 64; mask <<= 1) lsum += __shfl_xor(lsum, mask, 64);
      if (tid == 0) {
        m_arr[b * NTILES + t_idx] = m;
        l_arr[b * NTILES + t_idx] = lsum;
      }
      // wsum: wave owns chunks wv*16..+15; lane = (q = lane>>4, chl = lane&15)
      const int q = lane >> 4;
      const int ch = wv * 16 + (lane & 15);
      float wacc[8];
#pragma unroll
      for (int j = 0; j < 8; ++j) wacc[j] = 0.f;
#pragma unroll
      for (int k = 0; k < 16; ++k) {
        const int row = q * 16 + k;
        const float pr = __shfl(p, row, 64);
        half8 xv = *(const half8*)(xcur + row * D_DIM + ((ch ^ (row & 7)) * 8));
#pragma unroll
        for (int j = 0; j < 8; ++j) wacc[j] += pr * (float)xv[j];
      }
#pragma unroll
      for (int j = 0; j < 8; ++j) wacc[j] += __shfl_xor(wacc[j], 16, 64);
#pragma unroll
      for (int j = 0; j < 8; ++j) wacc[j] += __shfl_xor(wacc[j], 32, 64);
      if (q == 0) {
        float* ob = acc_arr + ((size_t)(b * NTILES + t_idx)) * D_DIM + ch * 8;
        *(f32x4*)(ob) = (f32x4){wacc[0], wacc[1], wacc[2], wacc[3]};
        *(f32x4*)(ob + 4) = (f32x4){wacc[4], wacc[5], wacc[6], wacc[7]};
      }
    }

    // ---- consume B into xnxt (all waves)
    if (pf) consume_batch(xnxt, 4);

    BAR();   // B: xnxt complete; xcur reads done -> buffers swap safely
  }
}

__global__ void __launch_bounds__(512)
combine_kernel(const float* __restrict__ m_arr, const float* __restrict__ l_arr,
               const float* __restrict__ acc_arr, float* __restrict__ out) {
  __shared__ float ml[NTILES], ls[NTILES], wl[NTILES];
  const int b = blockIdx.x, tid = threadIdx.x;
  if (tid < NTILES) {
    ml[tid] = m_arr[b * NTILES + tid];
    ls[tid] = l_arr[b * NTILES + tid];
  }
  __syncthreads();
  float M = -1e30f;
  for (int i = 0; i < NTILES; ++i) M = fmaxf(M, ml[i]);
  if (tid < NTILES) wl[tid] = __expf(ml[tid] - M);
  __syncthreads();
  float L = 0.f;
  for (int i = 0; i < NTILES; ++i) L += wl[i] * ls[i];
  float sum = 0.f;
  const size_t base = (size_t)b * NTILES * D_DIM + tid;
  for (int i = 0; i < NTILES; ++i) sum += wl[i] * acc_arr[base + (size_t)i * D_DIM];
  out[b * D_DIM + tid] = sum / L;
}

extern "C" void kernel_launch(void* const* d_in, const int* in_sizes, int n_in,
                              void* d_out, int out_size, void* d_ws, size_t ws_size,
                              hipStream_t stream) {
  const float* x = (const float*)d_in[0];
  const float* h = (const float*)d_in[1];
  const float* Wx = (const float*)d_in[2];
  const float* bx = (const float*)d_in[3];
  const float* Wh = (const float*)d_in[4];
  const float* Wt = (const float*)d_in[5];
  // d_in[6] = bt: unused (softmax shift-invariant)

  char* ws = (char*)d_ws;
  _Float16* Wp = (_Float16*)ws;                               // 262144 B (packed)
  float* whb = (float*)(ws + 262144);                         // 65536 B
  float* m_arr = (float*)(ws + 262144 + 65536);               // 32768 B
  float* l_arr = (float*)(ws + 262144 + 65536 + 32768);       // 32768 B
  float* acc_arr = (float*)(ws + 262144 + 65536 + 65536);     // 16.8 MB

  hipFuncSetAttribute(reinterpret_cast<const void*>(paa_main),
                      hipFuncAttributeMaxDynamicSharedMemorySize, SMEM_MAIN);

  hipLaunchKernelGGL(convw_kernel, dim3(64), dim3(256), 0, stream, Wx, Wp);
  hipLaunchKernelGGL(whb_kernel, dim3(B_DIM), dim3(256), 0, stream, h, Wh, bx, whb);
  hipLaunchKernelGGL(paa_main, dim3(NBLK), dim3(512), SMEM_MAIN, stream,
                     x, Wp, whb, Wt, m_arr, l_arr, acc_arr);
  hipLaunchKernelGGL(combine_kernel, dim3(B_DIM), dim3(512), 0, stream,
                     m_arr, l_arr, acc_arr, (float*)d_out);
}

// Round 12
// 368.002 us; speedup vs baseline: 4.4294x; 1.8988x over previous
//
#include <hip/hip_runtime.h>

// PositionAwareAttention: S=8192, B=64, D=512, A=256, all fp32 I/O.
// R12 = R11 with the staging bug fixed (R11 staged only chunks 0..31; the
// K-loop read uninitialized LDS -> NaN). Structure: R4's die-after-one-tile
// blocks with the tile halved: BM=32, 256 thr, 33 KB LDS -> 4 blocks/CU.
// HW multiplexes 4 independent blocks' stage/compute/tail phases per CU ->
// HBM duty ~4x0.43 > 1 => saturated. W packed (R4 layout) + streamed from
// global; swizzled fp16 x tile feeds MFMA and the weighted sum.
// k3 combines 256 tile-partials per b. bt omitted (softmax shift-invariant).

#define S_DIM 8192
#define B_DIM 64
#define D_DIM 512
#define A_DIM 256
#define BM 32
#define NTILES 256            // S / BM

typedef _Float16 half8 __attribute__((ext_vector_type(8)));
typedef float f32x4 __attribute__((ext_vector_type(4)));

__device__ __forceinline__ float tanh_fast(float x) {
  // tanh(x) = 1 - 2/(exp(2x)+1); exp->inf/0 saturates correctly to +/-1
  float e = __expf(2.0f * x);
  return 1.0f - 2.0f * __builtin_amdgcn_rcpf(e + 1.0f);
}

// Pack Wx (A=256 x K=512 f32) -> fp16 fragment tiles (R4 layout).
// elem (a=ta*16+fr, k=tk*32+fg*8+j) at Wp[(ta*16+tk)*512 + (fg*16+fr)*8 + j]
__global__ void __launch_bounds__(256)
convw_kernel(const float* __restrict__ Wx, _Float16* __restrict__ Wp) {
  const int idx = (blockIdx.x * 256 + threadIdx.x) * 8;
  const int a = idx >> 9;
  const int k = idx & 511;
  f32x4 va = *(const f32x4*)(Wx + idx);
  f32x4 vb = *(const f32x4*)(Wx + idx + 4);
  half8 hx;
#pragma unroll
  for (int i = 0; i < 4; ++i) { hx[i] = (_Float16)va[i]; hx[4 + i] = (_Float16)vb[i]; }
  const int ta = a >> 4, fr = a & 15;
  const int tk = k >> 5, fg = (k >> 3) & 3;
  *(half8*)(Wp + (ta * 16 + tk) * 512 + (fg * 16 + fr) * 8) = hx;
}

__global__ void __launch_bounds__(256)
whb_kernel(const float* __restrict__ h, const float* __restrict__ Wh,
           const float* __restrict__ bx, float* __restrict__ whb) {
  __shared__ float hs[D_DIM];
  const int b = blockIdx.x, tid = threadIdx.x;
  hs[tid] = h[b * D_DIM + tid];
  hs[tid + 256] = h[b * D_DIM + 256 + tid];
  __syncthreads();
  const int g = tid >> 4, i = tid & 15;
  for (int pass = 0; pass < 16; ++pass) {
    const int a = pass * 16 + g;
    const f32x4* wrow = (const f32x4*)(Wh + (size_t)a * D_DIM);
    float dot = 0.f;
#pragma unroll
    for (int k = 0; k < 8; ++k) {
      f32x4 wv = wrow[i + k * 16];
      f32x4 hv = *(const f32x4*)(hs + (i + k * 16) * 4);
      dot += wv[0] * hv[0] + wv[1] * hv[1] + wv[2] * hv[2] + wv[3] * hv[3];
    }
#pragma unroll
    for (int mask = 1; mask < 16; mask <<= 1) dot += __shfl_xor(dot, mask, 64);
    if (i == 0) whb[b * A_DIM + a] = dot + bx[a];
  }
}

__global__ void __launch_bounds__(256, 4)
paa_main(const float* __restrict__ x, const _Float16* __restrict__ Wp,
         const float* __restrict__ whb, const float* __restrict__ Wt,
         float* __restrict__ m_arr, float* __restrict__ l_arr,
         float* __restrict__ acc_arr) {
  __shared__ _Float16 xs[BM * D_DIM];     // [32][512] f16, 16B-chunk XOR swizzle (32 KB)
  __shared__ float scorep[4 * BM];        // [4 acol-groups][32 rows]

  const int tid = threadIdx.x;            // 0..255
  const int lane = tid & 63;
  const int wv = tid >> 6;                // 0..3 (wave = 32 rows x 64 acols)
  const int b = blockIdx.x;
  const int tile = blockIdx.y;

  const int fr = lane & 15, fg = lane >> 4;
  const int akey = fr & 7;
  // wave's packed-W base: acols [wv*64, wv*64+64), lane-contiguous 1 KB frags
  const _Float16* wp = Wp + wv * (4 * 16 * 512) + lane * 8;

  // epilogue constants, hoisted (per-lane acol scalars for nf=0..3)
  float wt_a[4], whb_a[4];
#pragma unroll
  for (int nf = 0; nf < 4; ++nf) {
    wt_a[nf]  = Wt[wv * 64 + nf * 16 + fr];
    whb_a[nf] = whb[b * A_DIM + wv * 64 + nf * 16 + fr];
  }

  // ---- stage: 32 rows x 512 f32 -> swizzled fp16 LDS.
  // Thread = (srow 0..31, sseg 0..7); pair p covers f32 cols p*64+sseg*8..+7
  // -> fp16 chunk ch = p*8+sseg. p = 0..7 covers ALL 64 chunks (R11 bug: 0..3).
  const int srow = tid >> 3, sseg = tid & 7;
  const int skey = srow & 7;
  {
    const float* rp = x + ((size_t)(tile * BM + srow) * B_DIM + b) * D_DIM;
    f32x4 sa[4], sb[4];
#pragma unroll
    for (int p = 0; p < 4; ++p) {
      sa[p] = *(const f32x4*)(rp + p * 64 + sseg * 8);
      sb[p] = *(const f32x4*)(rp + p * 64 + sseg * 8 + 4);
    }
#pragma unroll
    for (int p = 0; p < 4; ++p) {
      half8 hx;
#pragma unroll
      for (int j = 0; j < 4; ++j) { hx[j] = (_Float16)sa[p][j]; hx[4 + j] = (_Float16)sb[p][j]; }
      const int ch = p * 8 + sseg;
      *(half8*)(xs + srow * D_DIM + ((ch ^ skey) * 8)) = hx;
    }
#pragma unroll
    for (int p = 0; p < 4; ++p) {
      sa[p] = *(const f32x4*)(rp + (4 + p) * 64 + sseg * 8);
      sb[p] = *(const f32x4*)(rp + (4 + p) * 64 + sseg * 8 + 4);
    }
#pragma unroll
    for (int p = 0; p < 4; ++p) {
      half8 hx;
#pragma unroll
      for (int j = 0; j < 4; ++j) { hx[j] = (_Float16)sa[p][j]; hx[4 + j] = (_Float16)sb[p][j]; }
      const int ch = (4 + p) * 8 + sseg;
      *(half8*)(xs + srow * D_DIM + ((ch ^ skey) * 8)) = hx;
    }
  }
  __syncthreads();

  // ---- K-loop: A-frags from LDS, B-frags from packed global (L2); no barriers
  f32x4 acc[2][4];
#pragma unroll
  for (int mi = 0; mi < 2; ++mi)
#pragma unroll
    for (int nf = 0; nf < 4; ++nf) acc[mi][nf] = (f32x4){0.f, 0.f, 0.f, 0.f};
#pragma unroll
  for (int tk = 0; tk < 16; ++tk) {
    const int slot = ((tk * 4 + fg) ^ akey) * 8;
    half8 af0 = *(const half8*)(xs + (fr) * D_DIM + slot);
    half8 af1 = *(const half8*)(xs + (16 + fr) * D_DIM + slot);
    half8 bf0 = *(const half8*)(wp + (0 * 16 + tk) * 512);
    half8 bf1 = *(const half8*)(wp + (1 * 16 + tk) * 512);
    half8 bf2 = *(const half8*)(wp + (2 * 16 + tk) * 512);
    half8 bf3 = *(const half8*)(wp + (3 * 16 + tk) * 512);
    acc[0][0] = __builtin_amdgcn_mfma_f32_16x16x32_f16(af0, bf0, acc[0][0], 0, 0, 0);
    acc[0][1] = __builtin_amdgcn_mfma_f32_16x16x32_f16(af0, bf1, acc[0][1], 0, 0, 0);
    acc[0][2] = __builtin_amdgcn_mfma_f32_16x16x32_f16(af0, bf2, acc[0][2], 0, 0, 0);
    acc[0][3] = __builtin_amdgcn_mfma_f32_16x16x32_f16(af0, bf3, acc[0][3], 0, 0, 0);
    acc[1][0] = __builtin_amdgcn_mfma_f32_16x16x32_f16(af1, bf0, acc[1][0], 0, 0, 0);
    acc[1][1] = __builtin_amdgcn_mfma_f32_16x16x32_f16(af1, bf1, acc[1][1], 0, 0, 0);
    acc[1][2] = __builtin_amdgcn_mfma_f32_16x16x32_f16(af1, bf2, acc[1][2], 0, 0, 0);
    acc[1][3] = __builtin_amdgcn_mfma_f32_16x16x32_f16(af1, bf3, acc[1][3], 0, 0, 0);
  }

  // ---- epilogue: score partial for this wave's 64 acols (C frag: row=fg*4+r)
  {
    float part[2][4];
#pragma unroll
    for (int mi = 0; mi < 2; ++mi)
#pragma unroll
      for (int r = 0; r < 4; ++r) part[mi][r] = 0.f;
#pragma unroll
    for (int nf = 0; nf < 4; ++nf)
#pragma unroll
      for (int mi = 0; mi < 2; ++mi)
#pragma unroll
        for (int r = 0; r < 4; ++r)
          part[mi][r] += wt_a[nf] * tanh_fast(acc[mi][nf][r] + whb_a[nf]);
#pragma unroll
    for (int mask = 1; mask < 16; mask <<= 1)
#pragma unroll
      for (int mi = 0; mi < 2; ++mi)
#pragma unroll
        for (int r = 0; r < 4; ++r) part[mi][r] += __shfl_xor(part[mi][r], mask, 64);
    if (fr == 0) {
#pragma unroll
      for (int mi = 0; mi < 2; ++mi)
#pragma unroll
        for (int r = 0; r < 4; ++r)
          scorep[wv * BM + mi * 16 + fg * 4 + r] = part[mi][r];
    }
  }
  __syncthreads();

  // ---- tile-local softmax (32 rows; both 32-lane halves compute identically)
  const int rl = lane & 31;
  float sv = scorep[rl] + scorep[BM + rl] + scorep[2 * BM + rl] + scorep[3 * BM + rl];
  float m = sv;
#pragma unroll
  for (int mask = 1; mask < 32; mask <<= 1) m = fmaxf(m, __shfl_xor(m, mask, 64));
  float p = __expf(sv - m);
  float lsum = p;
#pragma unroll
  for (int mask = 1; mask < 32; mask <<= 1) lsum += __shfl_xor(lsum, mask, 64);
  if (tid == 0) {
    m_arr[b * NTILES + tile] = m;
    l_arr[b * NTILES + tile] = lsum;
  }

  // ---- weighted sum from resident tile: wave owns 16 chunks (128 cols)
  {
    const int q = lane >> 4;                 // 4 row-groups of 8
    const int ch = wv * 16 + (lane & 15);    // chunk 0..63
    float wacc[8];
#pragma unroll
    for (int j = 0; j < 8; ++j) wacc[j] = 0.f;
#pragma unroll
    for (int k = 0; k < 8; ++k) {
      const int row = q * 8 + k;
      const float pr = __shfl(p, row, 64);
      half8 xv = *(const half8*)(xs + row * D_DIM + ((ch ^ (row & 7)) * 8));
#pragma unroll
      for (int j = 0; j < 8; ++j) wacc[j] += pr * (float)xv[j];
    }
#pragma unroll
    for (int j = 0; j < 8; ++j) wacc[j] += __shfl_xor(wacc[j], 16, 64);
#pragma unroll
    for (int j = 0; j < 8; ++j) wacc[j] += __shfl_xor(wacc[j], 32, 64);
    if (lane < 16) {
      float* ob = acc_arr + ((size_t)(b * NTILES + tile)) * D_DIM + ch * 8;
      *(f32x4*)(ob) = (f32x4){wacc[0], wacc[1], wacc[2], wacc[3]};
      *(f32x4*)(ob + 4) = (f32x4){wacc[4], wacc[5], wacc[6], wacc[7]};
    }
  }
}

__global__ void __launch_bounds__(512)
combine_kernel(const float* __restrict__ m_arr, const float* __restrict__ l_arr,
               const float* __restrict__ acc_arr, float* __restrict__ out) {
  __shared__ float ml[NTILES], ls[NTILES], wl[NTILES];
  const int b = blockIdx.x, tid = threadIdx.x;
  if (tid < NTILES) {
    ml[tid] = m_arr[b * NTILES + tid];
    ls[tid] = l_arr[b * NTILES + tid];
  }
  __syncthreads();
  float M = -1e30f;
  for (int i = 0; i < NTILES; ++i) M = fmaxf(M, ml[i]);
  if (tid < NTILES) wl[tid] = __expf(ml[tid] - M);
  __syncthreads();
  float L = 0.f;
  for (int i = 0; i < NTILES; ++i) L += wl[i] * ls[i];
  float sum = 0.f;
  const size_t base = (size_t)b * NTILES * D_DIM + tid;
  for (int i = 0; i < NTILES; ++i) sum += wl[i] * acc_arr[base + (size_t)i * D_DIM];
  out[b * D_DIM + tid] = sum / L;
}

extern "C" void kernel_launch(void* const* d_in, const int* in_sizes, int n_in,
                              void* d_out, int out_size, void* d_ws, size_t ws_size,
                              hipStream_t stream) {
  const float* x = (const float*)d_in[0];
  const float* h = (const float*)d_in[1];
  const float* Wx = (const float*)d_in[2];
  const float* bx = (const float*)d_in[3];
  const float* Wh = (const float*)d_in[4];
  const float* Wt = (const float*)d_in[5];
  // d_in[6] = bt: unused (softmax shift-invariant)

  char* ws = (char*)d_ws;
  _Float16* Wp = (_Float16*)ws;                               // 262144 B (packed)
  float* whb = (float*)(ws + 262144);                         // 65536 B
  float* m_arr = (float*)(ws + 262144 + 65536);               // 65536 B
  float* l_arr = (float*)(ws + 262144 + 65536 + 65536);       // 65536 B
  float* acc_arr = (float*)(ws + 262144 + 3 * 65536);         // 33.6 MB

  hipLaunchKernelGGL(convw_kernel, dim3(64), dim3(256), 0, stream, Wx, Wp);
  hipLaunchKernelGGL(whb_kernel, dim3(B_DIM), dim3(256), 0, stream, h, Wh, bx, whb);
  hipLaunchKernelGGL(paa_main, dim3(B_DIM, NTILES), dim3(256), 0, stream,
                     x, Wp, whb, Wt, m_arr, l_arr, acc_arr);
  hipLaunchKernelGGL(combine_kernel, dim3(B_DIM), dim3(512), 0, stream,
                     m_arr, l_arr, acc_arr, (float*)d_out);
}